// Round 2
// baseline (996.563 us; speedup 1.0000x reference)
//
#include <hip/hip_runtime.h>
#include <math.h>

#define N_NODES 8192
#define N_FEAT  256
#define N_EDGES 131072
#define N_DIR   (2*N_EDGES)

// ---------- helpers ----------

// ECL-CC representative with path compression (labels only decrease -> plain
// stores are safe; see Jaiganesh & Burtscher 2018).
__device__ __forceinline__ int rep(int v, int* __restrict__ label){
  int curr = label[v];
  if (curr != v){
    int prev = v, next;
    while (curr > (next = label[curr])){
      label[prev] = next;
      prev = curr;
      curr = next;
    }
  }
  return curr;
}

// directed edge k: s = ei[k]; d = ei[k<E ? k+E : k-E]
__device__ __forceinline__ void edge_sd(const int* __restrict__ ei, int k, int& s, int& d){
  s = ei[k];
  d = (k < N_EDGES) ? ei[k + N_EDGES] : ei[k - N_EDGES];
}

// ---------- kernels ----------

__global__ void k_init(int* __restrict__ label, int* __restrict__ cnt, int* __restrict__ deg){
  int i = blockIdx.x * blockDim.x + threadIdx.x;
  if (i < N_NODES){ label[i] = i; cnt[i] = 0; deg[i] = 0; }
}

// p1[i] = dot(x[i], w[:256]); p2[i] = dot(x[i], w[256:])  (f64 accumulate)
__global__ void k_proj(const float* __restrict__ x, const float* __restrict__ w,
                       float* __restrict__ p1, float* __restrict__ p2){
  int i = blockIdx.x;
  int t = threadIdx.x;                  // 256 threads
  float v = x[(size_t)i * N_FEAT + t];
  double a = (double)v * (double)w[t];
  double b = (double)v * (double)w[N_FEAT + t];
  for (int off = 32; off; off >>= 1){
    a += __shfl_down(a, off);
    b += __shfl_down(b, off);
  }
  __shared__ double sa[4], sb[4];
  int wid = t >> 6, lane = t & 63;
  if (lane == 0){ sa[wid] = a; sb[wid] = b; }
  __syncthreads();
  if (t == 0){
    p1[i] = (float)(sa[0] + sa[1] + sa[2] + sa[3]);
    p2[i] = (float)(sb[0] + sb[1] + sb[2] + sb[3]);
  }
}

// e per directed edge; count incoming non-self edges; contract degree
__global__ void k_edges(const int* __restrict__ ei, const float* __restrict__ p1,
                        const float* __restrict__ p2, const float* __restrict__ lb,
                        float* __restrict__ e_val, int* __restrict__ cnt, int* __restrict__ deg){
  int k = blockIdx.x * blockDim.x + threadIdx.x;
  if (k >= N_DIR) return;
  int s, d; edge_sd(ei, k, s, d);
  if (s == d){ e_val[k] = 0.0f; return; }
  float z = p1[s] + p2[d] + lb[0];
  float e = tanhf(z);
  e_val[k] = e;
  atomicAdd(&cnt[d], 1);
  if (e > 0.0f){
    atomicAdd(&deg[s], 1);
    atomicAdd(&deg[d], 1);
  }
}

// exclusive scan of cnt[8192] -> row_start[8193], copy to cursor
__global__ void k_scan(const int* __restrict__ cnt, int* __restrict__ row_start,
                       int* __restrict__ cursor){
  __shared__ int wsum[1024];
  int t = threadIdx.x;                  // 1024 threads, 8 elems each
  int base = t * 8;
  int f[8]; int s = 0;
  #pragma unroll
  for (int j = 0; j < 8; ++j){ f[j] = cnt[base + j]; s += f[j]; }
  wsum[t] = s;
  __syncthreads();
  for (int off = 1; off < 1024; off <<= 1){
    int v = (t >= off) ? wsum[t - off] : 0;
    __syncthreads();
    wsum[t] += v;
    __syncthreads();
  }
  int run = wsum[t] - s;                // exclusive prefix for this chunk
  #pragma unroll
  for (int j = 0; j < 8; ++j){
    row_start[base + j] = run;
    cursor[base + j]    = run;
    run += f[j];
  }
  if (t == 1023) row_start[N_NODES] = run;
}

// CSR fill by destination
__global__ void k_fill(const int* __restrict__ ei, const float* __restrict__ e_val,
                       int* __restrict__ cursor, int* __restrict__ esrc, float* __restrict__ evs){
  int k = blockIdx.x * blockDim.x + threadIdx.x;
  if (k >= N_DIR) return;
  int s, d; edge_sd(ei, k, s, d);
  if (s == d) return;
  int slot = atomicAdd(&cursor[d], 1);
  esrc[slot] = s;
  evs[slot]  = e_val[k];
}

// ECL-CC union: path-compressing find + atomicCAS hook (larger root -> smaller).
// Exact in one pass; converged root == min node index of component.
__global__ void k_union(const int* __restrict__ ei, const float* __restrict__ e_val,
                        int* label){
  int k = blockIdx.x * blockDim.x + threadIdx.x;
  if (k >= N_DIR) return;
  if (!(e_val[k] > 0.0f)) return;       // self edges stored 0 -> skipped
  int s, d; edge_sd(ei, k, s, d);
  int vstat = rep(s, label);
  int ostat = rep(d, label);
  bool repeat;
  do {
    repeat = false;
    if (vstat != ostat){
      int ret;
      if (vstat < ostat){
        if ((ret = atomicCAS(&label[ostat], ostat, vstat)) != ostat){
          ostat = ret; repeat = true;
        }
      } else {
        if ((ret = atomicCAS(&label[vstat], vstat, ostat)) != vstat){
          vstat = ret; repeat = true;
        }
      }
    }
  } while (repeat);
}

__global__ void k_compress(int* __restrict__ label){
  int i = blockIdx.x * blockDim.x + threadIdx.x;
  if (i >= N_NODES) return;
  int l = label[i];
  while (true){ int p = label[l]; if (p == l) break; l = p; }
  label[i] = l;
}

// rank roots (scan in LDS), produce cluster ids + int outputs (as floats)
__global__ void k_cluster(const int* __restrict__ label, const int* __restrict__ batch,
                          int* __restrict__ cluster_i, float* __restrict__ out_cluster,
                          float* __restrict__ out_batch){
  __shared__ int R[N_NODES];            // 32 KB
  __shared__ int wsum[1024];
  int t = threadIdx.x;                  // 1024 threads, 8 elems each
  int base = t * 8;
  int f[8]; int s = 0;
  #pragma unroll
  for (int j = 0; j < 8; ++j){ f[j] = (label[base + j] == base + j) ? 1 : 0; s += f[j]; }
  wsum[t] = s;
  __syncthreads();
  for (int off = 1; off < 1024; off <<= 1){
    int v = (t >= off) ? wsum[t - off] : 0;
    __syncthreads();
    wsum[t] += v;
    __syncthreads();
  }
  int run = wsum[t] - s;
  #pragma unroll
  for (int j = 0; j < 8; ++j){ run += f[j]; R[base + j] = run; }  // inclusive cumsum
  __syncthreads();
  #pragma unroll
  for (int j = 0; j < 8; ++j){
    int i = base + j;
    int c = R[label[i]] - 1;
    cluster_i[i] = c;
    out_cluster[i] = (float)c;
    out_batch[c] = (float)batch[i];     // batch uniform; duplicates benign
  }
}

// y[i,:] = (isolated ? x[i,:] : 0) + sum_{edges s->i} e * x[s,:]
__global__ void k_y(const float* __restrict__ x, const float* __restrict__ evs,
                    const int* __restrict__ esrc, const int* __restrict__ row_start,
                    const int* __restrict__ deg, float* __restrict__ y){
  int i = blockIdx.x;
  int t = threadIdx.x;                  // 256 threads = feature dim
  int a = row_start[i], b = row_start[i + 1];
  float acc = (deg[i] == 0) ? x[(size_t)i * N_FEAT + t] : 0.0f;
  for (int j = a; j < b; ++j){
    acc += evs[j] * x[(size_t)esrc[j] * N_FEAT + t];
  }
  y[(size_t)i * N_FEAT + t] = acc;
}

// X_new[cluster[i],:] += y[i,:]  (run-length register accumulation, then atomicAdd)
__global__ void k_xnew(const float* __restrict__ y, const int* __restrict__ cluster_i,
                       float* __restrict__ Xn){
  int t = threadIdx.x;                  // 256 threads
  int node0 = blockIdx.x * 32;
  float acc = 0.0f;
  int cur = cluster_i[node0];
  for (int j = 0; j < 32; ++j){
    int node = node0 + j;
    int c = cluster_i[node];
    if (c != cur){
      atomicAdd(&Xn[(size_t)cur * N_FEAT + t], acc);
      acc = 0.0f; cur = c;
    }
    acc += y[(size_t)node * N_FEAT + t];
  }
  atomicAdd(&Xn[(size_t)cur * N_FEAT + t], acc);
}

// A_c[cs,cd] += 1 per directed non-self edge crossing clusters (diag zeroed by ref)
__global__ void k_ac(const int* __restrict__ ei, const int* __restrict__ cluster_i,
                     float* __restrict__ Ac){
  int k = blockIdx.x * blockDim.x + threadIdx.x;
  if (k >= N_DIR) return;
  int s, d; edge_sd(ei, k, s, d);
  if (s == d) return;
  int cs = cluster_i[s], cd = cluster_i[d];
  if (cs != cd) atomicAdd(&Ac[(size_t)cs * N_NODES + cd], 1.0f);
}

// ---------- launcher ----------

extern "C" void kernel_launch(void* const* d_in, const int* in_sizes, int n_in,
                              void* d_out, int out_size, void* d_ws, size_t ws_size,
                              hipStream_t stream){
  const float* x     = (const float*)d_in[0];
  const int*   ei    = (const int*)  d_in[1];
  const int*   batch = (const int*)  d_in[2];
  const float* lw    = (const float*)d_in[3];
  const float* lb    = (const float*)d_in[4];

  float* out = (float*)d_out;
  float* Xn  = out;                                       // 8192*256
  float* Ac  = Xn + (size_t)N_NODES * N_FEAT;             // 8192*8192
  float* ob  = Ac + (size_t)N_NODES * N_NODES;            // 8192 (new_batch)
  float* oc  = ob + N_NODES;                              // 8192 (cluster)

  char* w = (char*)d_ws;
  float* p1        = (float*)w; w += (size_t)N_NODES * 4;
  float* p2        = (float*)w; w += (size_t)N_NODES * 4;
  float* e_val     = (float*)w; w += (size_t)N_DIR   * 4;
  int*   cnt       = (int*)  w; w += (size_t)N_NODES * 4;
  int*   cursor    = (int*)  w; w += (size_t)N_NODES * 4;
  int*   row_start = (int*)  w; w += (size_t)(N_NODES + 8) * 4;
  int*   deg       = (int*)  w; w += (size_t)N_NODES * 4;
  int*   label     = (int*)  w; w += (size_t)N_NODES * 4;
  int*   cluster_i = (int*)  w; w += (size_t)N_NODES * 4;
  int*   esrc      = (int*)  w; w += (size_t)N_DIR   * 4;
  float* evs       = (float*)w; w += (size_t)N_DIR   * 4;
  float* y         = (float*)w; w += (size_t)N_NODES * N_FEAT * 4;

  // zero entire output (covers X_new, A_c, new_batch, cluster slots)
  hipMemsetAsync(d_out, 0, (size_t)out_size * sizeof(float), stream);

  k_init    <<<(N_NODES + 255) / 256, 256, 0, stream>>>(label, cnt, deg);
  k_proj    <<<N_NODES, 256, 0, stream>>>(x, lw, p1, p2);
  k_edges   <<<N_DIR / 256, 256, 0, stream>>>(ei, p1, p2, lb, e_val, cnt, deg);
  k_scan    <<<1, 1024, 0, stream>>>(cnt, row_start, cursor);
  k_fill    <<<N_DIR / 256, 256, 0, stream>>>(ei, e_val, cursor, esrc, evs);
  k_union   <<<N_DIR / 256, 256, 0, stream>>>(ei, e_val, label);
  k_compress<<<(N_NODES + 255) / 256, 256, 0, stream>>>(label);
  k_cluster <<<1, 1024, 0, stream>>>(label, batch, cluster_i, oc, ob);
  k_y       <<<N_NODES, 256, 0, stream>>>(x, evs, esrc, row_start, deg, y);
  k_xnew    <<<N_NODES / 32, 256, 0, stream>>>(y, cluster_i, Xn);
  k_ac      <<<N_DIR / 256, 256, 0, stream>>>(ei, cluster_i, Ac);
}

// Round 3
// 398.857 us; speedup vs baseline: 2.4985x; 2.4985x over previous
//
#include <hip/hip_runtime.h>
#include <math.h>

#define N_NODES 8192
#define N_FEAT  256
#define N_EDGES 131072
#define N_DIR   (2*N_EDGES)

// ---------- helpers ----------

// directed edge k: s = ei[k]; d = ei[k<E ? k+E : k-E]
__device__ __forceinline__ void edge_sd(const int* __restrict__ ei, int k, int& s, int& d){
  s = ei[k];
  d = (k < N_EDGES) ? ei[k + N_EDGES] : ei[k - N_EDGES];
}

// ECL-CC representative with path compression, LDS variant.
__device__ __forceinline__ int rep_lds(int v, int* L){
  int curr = L[v];
  if (curr != v){
    int prev = v, next;
    while (curr > (next = L[curr])){
      L[prev] = next;
      prev = curr;
      curr = next;
    }
  }
  return curr;
}

// ---------- kernels ----------

__global__ void k_init(int* __restrict__ cnt, int* __restrict__ deg){
  int i = blockIdx.x * blockDim.x + threadIdx.x;
  if (i < N_NODES){ cnt[i] = 0; deg[i] = 0; }
}

// p1[i] = dot(x[i], w[:256]); p2[i] = dot(x[i], w[256:])  (f64 accumulate)
__global__ void k_proj(const float* __restrict__ x, const float* __restrict__ w,
                       float* __restrict__ p1, float* __restrict__ p2){
  int i = blockIdx.x;
  int t = threadIdx.x;                  // 256 threads
  float v = x[(size_t)i * N_FEAT + t];
  double a = (double)v * (double)w[t];
  double b = (double)v * (double)w[N_FEAT + t];
  for (int off = 32; off; off >>= 1){
    a += __shfl_down(a, off);
    b += __shfl_down(b, off);
  }
  __shared__ double sa[4], sb[4];
  int wid = t >> 6, lane = t & 63;
  if (lane == 0){ sa[wid] = a; sb[wid] = b; }
  __syncthreads();
  if (t == 0){
    p1[i] = (float)(sa[0] + sa[1] + sa[2] + sa[3]);
    p2[i] = (float)(sb[0] + sb[1] + sb[2] + sb[3]);
  }
}

// e per directed edge; count incoming non-self edges; contract degree
__global__ void k_edges(const int* __restrict__ ei, const float* __restrict__ p1,
                        const float* __restrict__ p2, const float* __restrict__ lb,
                        float* __restrict__ e_val, int* __restrict__ cnt, int* __restrict__ deg){
  int k = blockIdx.x * blockDim.x + threadIdx.x;
  if (k >= N_DIR) return;
  int s, d; edge_sd(ei, k, s, d);
  if (s == d){ e_val[k] = 0.0f; return; }
  float z = p1[s] + p2[d] + lb[0];
  float e = tanhf(z);
  e_val[k] = e;
  atomicAdd(&cnt[d], 1);
  if (e > 0.0f){
    atomicAdd(&deg[s], 1);
    atomicAdd(&deg[d], 1);
  }
}

// exclusive scan of cnt[8192] -> row_start[8193], copy to cursor
__global__ void k_scan(const int* __restrict__ cnt, int* __restrict__ row_start,
                       int* __restrict__ cursor){
  __shared__ int wsum[1024];
  int t = threadIdx.x;                  // 1024 threads, 8 elems each
  int base = t * 8;
  int f[8]; int s = 0;
  #pragma unroll
  for (int j = 0; j < 8; ++j){ f[j] = cnt[base + j]; s += f[j]; }
  wsum[t] = s;
  __syncthreads();
  for (int off = 1; off < 1024; off <<= 1){
    int v = (t >= off) ? wsum[t - off] : 0;
    __syncthreads();
    wsum[t] += v;
    __syncthreads();
  }
  int run = wsum[t] - s;                // exclusive prefix for this chunk
  #pragma unroll
  for (int j = 0; j < 8; ++j){
    row_start[base + j] = run;
    cursor[base + j]    = run;
    run += f[j];
  }
  if (t == 1023) row_start[N_NODES] = run;
}

// CSR fill by destination
__global__ void k_fill(const int* __restrict__ ei, const float* __restrict__ e_val,
                       int* __restrict__ cursor, int* __restrict__ esrc, float* __restrict__ evs){
  int k = blockIdx.x * blockDim.x + threadIdx.x;
  if (k >= N_DIR) return;
  int s, d; edge_sd(ei, k, s, d);
  if (s == d) return;
  int slot = atomicAdd(&cursor[d], 1);
  esrc[slot] = s;
  evs[slot]  = e_val[k];
}

// Connected components entirely in LDS (one workgroup):
// ECL-CC union-find w/ path compression, flatten, rank roots, emit outputs.
__global__ void __launch_bounds__(1024) k_cc(
    const int* __restrict__ ei, const float* __restrict__ e_val,
    const int* __restrict__ batch,
    int* __restrict__ cluster_i, float* __restrict__ out_cluster,
    float* __restrict__ out_batch){
  __shared__ int L[N_NODES];            // 32 KB parent array
  __shared__ int wsum[1024];            // 4 KB scan buffer
  int t = threadIdx.x;

  for (int i = t; i < N_NODES; i += 1024) L[i] = i;
  __syncthreads();

  // union all contract edges (e>0; self edges have e_val==0)
  for (int k = t; k < N_DIR; k += 1024){
    if (!(e_val[k] > 0.0f)) continue;
    int s, d; edge_sd(ei, k, s, d);
    int vstat = rep_lds(s, L);
    int ostat = rep_lds(d, L);
    bool repeat;
    do {
      repeat = false;
      if (vstat != ostat){
        int ret;
        if (vstat < ostat){
          if ((ret = atomicCAS(&L[ostat], ostat, vstat)) != ostat){
            ostat = ret; repeat = true;
          }
        } else {
          if ((ret = atomicCAS(&L[vstat], vstat, ostat)) != vstat){
            vstat = ret; repeat = true;
          }
        }
      }
    } while (repeat);
  }
  __syncthreads();

  // flatten chains (root writes only shortcut, safe concurrently)
  int base = t * 8;
  int l_reg[8];
  #pragma unroll
  for (int j = 0; j < 8; ++j){
    int l = L[base + j];
    while (true){ int p = L[l]; if (p == l) break; l = p; }
    l_reg[j] = l;
  }
  __syncthreads();

  // rank roots: flag + block-wide scan (1024 threads x 8)
  int f[8]; int s = 0;
  #pragma unroll
  for (int j = 0; j < 8; ++j){ f[j] = (l_reg[j] == base + j) ? 1 : 0; s += f[j]; }
  wsum[t] = s;
  __syncthreads();
  for (int off = 1; off < 1024; off <<= 1){
    int v = (t >= off) ? wsum[t - off] : 0;
    __syncthreads();
    wsum[t] += v;
    __syncthreads();
  }
  int run = wsum[t] - s;                // exclusive prefix
  // store cluster id (rank-1 ... as rank, minus applied below) into root slots
  #pragma unroll
  for (int j = 0; j < 8; ++j){
    run += f[j];
    if (f[j]) L[base + j] = run - 1;    // root's cluster id
  }
  __syncthreads();

  #pragma unroll
  for (int j = 0; j < 8; ++j){
    int i = base + j;
    int c = L[l_reg[j]];
    cluster_i[i] = c;
    out_cluster[i] = (float)c;
    out_batch[c] = (float)batch[i];     // last-write-wins; batch uniform
  }
}

// y[i,:] = (isolated ? x[i,:] : 0) + sum_{edges s->i} e * x[s,:]
__global__ void k_y(const float* __restrict__ x, const float* __restrict__ evs,
                    const int* __restrict__ esrc, const int* __restrict__ row_start,
                    const int* __restrict__ deg, float* __restrict__ y){
  int i = blockIdx.x;
  int t = threadIdx.x;                  // 256 threads = feature dim
  int a = row_start[i], b = row_start[i + 1];
  float acc = (deg[i] == 0) ? x[(size_t)i * N_FEAT + t] : 0.0f;
  for (int j = a; j < b; ++j){
    acc += evs[j] * x[(size_t)esrc[j] * N_FEAT + t];
  }
  y[(size_t)i * N_FEAT + t] = acc;
}

// X_new[cluster[i],:] += y[i,:]  (run-length register accumulation, then atomicAdd)
__global__ void k_xnew(const float* __restrict__ y, const int* __restrict__ cluster_i,
                       float* __restrict__ Xn){
  int t = threadIdx.x;                  // 256 threads
  int node0 = blockIdx.x * 32;
  float acc = 0.0f;
  int cur = cluster_i[node0];
  for (int j = 0; j < 32; ++j){
    int node = node0 + j;
    int c = cluster_i[node];
    if (c != cur){
      atomicAdd(&Xn[(size_t)cur * N_FEAT + t], acc);
      acc = 0.0f; cur = c;
    }
    acc += y[(size_t)node * N_FEAT + t];
  }
  atomicAdd(&Xn[(size_t)cur * N_FEAT + t], acc);
}

// A_c[cs,cd] += 1 per directed non-self edge crossing clusters (diag zeroed by ref)
__global__ void k_ac(const int* __restrict__ ei, const int* __restrict__ cluster_i,
                     float* __restrict__ Ac){
  int k = blockIdx.x * blockDim.x + threadIdx.x;
  if (k >= N_DIR) return;
  int s, d; edge_sd(ei, k, s, d);
  if (s == d) return;
  int cs = cluster_i[s], cd = cluster_i[d];
  if (cs != cd) atomicAdd(&Ac[(size_t)cs * N_NODES + cd], 1.0f);
}

// ---------- launcher ----------

extern "C" void kernel_launch(void* const* d_in, const int* in_sizes, int n_in,
                              void* d_out, int out_size, void* d_ws, size_t ws_size,
                              hipStream_t stream){
  const float* x     = (const float*)d_in[0];
  const int*   ei    = (const int*)  d_in[1];
  const int*   batch = (const int*)  d_in[2];
  const float* lw    = (const float*)d_in[3];
  const float* lb    = (const float*)d_in[4];

  float* out = (float*)d_out;
  float* Xn  = out;                                       // 8192*256
  float* Ac  = Xn + (size_t)N_NODES * N_FEAT;             // 8192*8192
  float* ob  = Ac + (size_t)N_NODES * N_NODES;            // 8192 (new_batch)
  float* oc  = ob + N_NODES;                              // 8192 (cluster)

  char* w = (char*)d_ws;
  float* p1        = (float*)w; w += (size_t)N_NODES * 4;
  float* p2        = (float*)w; w += (size_t)N_NODES * 4;
  float* e_val     = (float*)w; w += (size_t)N_DIR   * 4;
  int*   cnt       = (int*)  w; w += (size_t)N_NODES * 4;
  int*   cursor    = (int*)  w; w += (size_t)N_NODES * 4;
  int*   row_start = (int*)  w; w += (size_t)(N_NODES + 8) * 4;
  int*   deg       = (int*)  w; w += (size_t)N_NODES * 4;
  int*   cluster_i = (int*)  w; w += (size_t)N_NODES * 4;
  int*   esrc      = (int*)  w; w += (size_t)N_DIR   * 4;
  float* evs       = (float*)w; w += (size_t)N_DIR   * 4;
  float* y         = (float*)w; w += (size_t)N_NODES * N_FEAT * 4;

  // zero entire output (covers X_new, A_c, new_batch, cluster slots)
  hipMemsetAsync(d_out, 0, (size_t)out_size * sizeof(float), stream);

  k_init  <<<(N_NODES + 255) / 256, 256, 0, stream>>>(cnt, deg);
  k_proj  <<<N_NODES, 256, 0, stream>>>(x, lw, p1, p2);
  k_edges <<<N_DIR / 256, 256, 0, stream>>>(ei, p1, p2, lb, e_val, cnt, deg);
  k_scan  <<<1, 1024, 0, stream>>>(cnt, row_start, cursor);
  k_fill  <<<N_DIR / 256, 256, 0, stream>>>(ei, e_val, cursor, esrc, evs);
  k_cc    <<<1, 1024, 0, stream>>>(ei, e_val, batch, cluster_i, oc, ob);
  k_y     <<<N_NODES, 256, 0, stream>>>(x, evs, esrc, row_start, deg, y);
  k_xnew  <<<N_NODES / 32, 256, 0, stream>>>(y, cluster_i, Xn);
  k_ac    <<<N_DIR / 256, 256, 0, stream>>>(ei, cluster_i, Ac);
}

// Round 4
// 274.788 us; speedup vs baseline: 3.6267x; 1.4515x over previous
//
#include <hip/hip_runtime.h>
#include <math.h>

#define N_NODES 8192
#define N_FEAT  256
#define N_EDGES 131072
#define N_DIR   (2*N_EDGES)

// ---------- helpers ----------

// directed edge k: s = ei[k]; d = ei[k<E ? k+E : k-E]
__device__ __forceinline__ void edge_sd(const int* __restrict__ ei, int k, int& s, int& d){
  s = ei[k];
  d = (k < N_EDGES) ? ei[k + N_EDGES] : ei[k - N_EDGES];
}

// ECL-CC representative with path compression, LDS variant.
__device__ __forceinline__ int rep_lds(int v, int* L){
  int curr = L[v];
  if (curr != v){
    int prev = v, next;
    while (curr > (next = L[curr])){
      L[prev] = next;
      prev = curr;
      curr = next;
    }
  }
  return curr;
}

// ---------- kernels ----------

__global__ void k_init(int* __restrict__ cnt, int* __restrict__ deg, int* __restrict__ np){
  int i = blockIdx.x * blockDim.x + threadIdx.x;
  if (i < N_NODES){ cnt[i] = 0; deg[i] = 0; }
  if (i == 0) *np = 0;
}

// p1[i] = dot(x[i], w[:256]); p2[i] = dot(x[i], w[256:])  (f64 accumulate)
__global__ void k_proj(const float* __restrict__ x, const float* __restrict__ w,
                       float* __restrict__ p1, float* __restrict__ p2){
  int i = blockIdx.x;
  int t = threadIdx.x;                  // 256 threads
  float v = x[(size_t)i * N_FEAT + t];
  double a = (double)v * (double)w[t];
  double b = (double)v * (double)w[N_FEAT + t];
  for (int off = 32; off; off >>= 1){
    a += __shfl_down(a, off);
    b += __shfl_down(b, off);
  }
  __shared__ double sa[4], sb[4];
  int wid = t >> 6, lane = t & 63;
  if (lane == 0){ sa[wid] = a; sb[wid] = b; }
  __syncthreads();
  if (t == 0){
    p1[i] = (float)(sa[0] + sa[1] + sa[2] + sa[3]);
    p2[i] = (float)(sb[0] + sb[1] + sb[2] + sb[3]);
  }
}

// e per directed edge; count incoming non-self; contract degree; emit packed
// contract pairs via wave-aggregated compaction.
__global__ void k_edges(const int* __restrict__ ei, const float* __restrict__ p1,
                        const float* __restrict__ p2, const float* __restrict__ lb,
                        float* __restrict__ e_val, int* __restrict__ cnt,
                        int* __restrict__ deg, unsigned int* __restrict__ pairs,
                        int* __restrict__ np){
  int k = blockIdx.x * blockDim.x + threadIdx.x;
  int s, d; edge_sd(ei, k, s, d);
  bool selfe = (s == d);
  float e = 0.0f;
  if (!selfe){
    float z = p1[s] + p2[d] + lb[0];
    e = tanhf(z);
    e_val[k] = e;
    atomicAdd(&cnt[d], 1);
    if (e > 0.0f){
      atomicAdd(&deg[s], 1);
      atomicAdd(&deg[d], 1);
    }
  }
  bool c = (!selfe) && (e > 0.0f);
  unsigned long long m = __ballot(c);
  if (m){
    int lane = threadIdx.x & 63;
    int leader = __ffsll((unsigned long long)m) - 1;
    int base = 0;
    if (lane == leader) base = atomicAdd(np, __popcll(m));
    base = __shfl(base, leader);
    if (c){
      int prefix = __popcll(m & ((1ull << lane) - 1ull));
      pairs[base + prefix] = ((unsigned int)s << 13) | (unsigned int)d;
    }
  }
}

// exclusive scan of cnt[8192] -> row_start[8193], copy to cursor
__global__ void k_scan(const int* __restrict__ cnt, int* __restrict__ row_start,
                       int* __restrict__ cursor){
  __shared__ int wsum[1024];
  int t = threadIdx.x;                  // 1024 threads, 8 elems each
  int base = t * 8;
  int f[8]; int s = 0;
  #pragma unroll
  for (int j = 0; j < 8; ++j){ f[j] = cnt[base + j]; s += f[j]; }
  wsum[t] = s;
  __syncthreads();
  for (int off = 1; off < 1024; off <<= 1){
    int v = (t >= off) ? wsum[t - off] : 0;
    __syncthreads();
    wsum[t] += v;
    __syncthreads();
  }
  int run = wsum[t] - s;                // exclusive prefix for this chunk
  #pragma unroll
  for (int j = 0; j < 8; ++j){
    row_start[base + j] = run;
    cursor[base + j]    = run;
    run += f[j];
  }
  if (t == 1023) row_start[N_NODES] = run;
}

// CSR fill by destination
__global__ void k_fill(const int* __restrict__ ei, const float* __restrict__ e_val,
                       int* __restrict__ cursor, int* __restrict__ esrc, float* __restrict__ evs){
  int k = blockIdx.x * blockDim.x + threadIdx.x;
  if (k >= N_DIR) return;
  int s, d; edge_sd(ei, k, s, d);
  if (s == d) return;
  int slot = atomicAdd(&cursor[d], 1);
  esrc[slot] = s;
  evs[slot]  = e_val[k];
}

// Connected components entirely in LDS (one workgroup), over the compacted
// contract-pair list, chunked with barrier-flatten so the steady state is
// a 2-LDS-read fast path.
__global__ void __launch_bounds__(1024) k_cc(
    const unsigned int* __restrict__ pairs, const int* __restrict__ np,
    const int* __restrict__ batch,
    int* __restrict__ cluster_i, float* __restrict__ out_cluster,
    float* __restrict__ out_batch){
  __shared__ int L[N_NODES];            // 32 KB parent array
  __shared__ int wsum[1024];            // 4 KB scan buffer
  int t = threadIdx.x;

  for (int i = t; i < N_NODES; i += 1024) L[i] = i;
  __syncthreads();

  int n = *np;
  const int CH = 16384;
  for (int cbase = 0; cbase < n; cbase += CH){
    int lim = (cbase + CH < n) ? (cbase + CH) : n;
    for (int k = cbase + t; k < lim; k += 1024){
      unsigned int p = pairs[k];
      int s = (int)(p >> 13), d = (int)(p & 8191u);
      int a = L[s], b = L[d];
      if (a == b) continue;             // fast path: already same component
      a = rep_lds(s, L);
      b = rep_lds(d, L);
      bool repeat;
      do {
        repeat = false;
        if (a != b){
          int ret;
          if (a < b){
            if ((ret = atomicCAS(&L[b], b, a)) != b){ b = ret; repeat = true; }
          } else {
            if ((ret = atomicCAS(&L[a], a, b)) != a){ a = ret; repeat = true; }
          }
        }
      } while (repeat);
    }
    __syncthreads();
    // full flatten (plain stores; safe between barriers)
    for (int i = t; i < N_NODES; i += 1024){
      int l = L[i];
      while (true){ int q = L[l]; if (q == l) break; l = q; }
      L[i] = l;
    }
    __syncthreads();
  }

  // L[i] is now the min-label root for every node
  int base = t * 8;
  int l_reg[8];
  #pragma unroll
  for (int j = 0; j < 8; ++j) l_reg[j] = L[base + j];
  __syncthreads();

  // rank roots: flag + block-wide scan (1024 threads x 8)
  int f[8]; int s = 0;
  #pragma unroll
  for (int j = 0; j < 8; ++j){ f[j] = (l_reg[j] == base + j) ? 1 : 0; s += f[j]; }
  wsum[t] = s;
  __syncthreads();
  for (int off = 1; off < 1024; off <<= 1){
    int v = (t >= off) ? wsum[t - off] : 0;
    __syncthreads();
    wsum[t] += v;
    __syncthreads();
  }
  int run = wsum[t] - s;                // exclusive prefix
  #pragma unroll
  for (int j = 0; j < 8; ++j){
    run += f[j];
    if (f[j]) L[base + j] = run - 1;    // root's cluster id
  }
  __syncthreads();

  #pragma unroll
  for (int j = 0; j < 8; ++j){
    int i = base + j;
    int c = L[l_reg[j]];
    cluster_i[i] = c;
    out_cluster[i] = (float)c;
    out_batch[c] = (float)batch[i];     // last-write-wins; batch uniform
  }
}

// y[i,:] = (isolated ? x[i,:] : 0) + sum_{edges s->i} e * x[s,:]
__global__ void k_y(const float* __restrict__ x, const float* __restrict__ evs,
                    const int* __restrict__ esrc, const int* __restrict__ row_start,
                    const int* __restrict__ deg, float* __restrict__ y){
  int i = blockIdx.x;
  int t = threadIdx.x;                  // 256 threads = feature dim
  int a = row_start[i], b = row_start[i + 1];
  float acc = (deg[i] == 0) ? x[(size_t)i * N_FEAT + t] : 0.0f;
  for (int j = a; j < b; ++j){
    acc += evs[j] * x[(size_t)esrc[j] * N_FEAT + t];
  }
  y[(size_t)i * N_FEAT + t] = acc;
}

// X_new[cluster[i],:] += y[i,:]  (run-length register accumulation, then atomicAdd)
__global__ void k_xnew(const float* __restrict__ y, const int* __restrict__ cluster_i,
                       float* __restrict__ Xn){
  int t = threadIdx.x;                  // 256 threads
  int node0 = blockIdx.x * 32;
  float acc = 0.0f;
  int cur = cluster_i[node0];
  for (int j = 0; j < 32; ++j){
    int node = node0 + j;
    int c = cluster_i[node];
    if (c != cur){
      atomicAdd(&Xn[(size_t)cur * N_FEAT + t], acc);
      acc = 0.0f; cur = c;
    }
    acc += y[(size_t)node * N_FEAT + t];
  }
  atomicAdd(&Xn[(size_t)cur * N_FEAT + t], acc);
}

// A_c[cs,cd] += 1 per directed non-self edge crossing clusters (diag zeroed by ref)
__global__ void k_ac(const int* __restrict__ ei, const int* __restrict__ cluster_i,
                     float* __restrict__ Ac){
  int k = blockIdx.x * blockDim.x + threadIdx.x;
  if (k >= N_DIR) return;
  int s, d; edge_sd(ei, k, s, d);
  if (s == d) return;
  int cs = cluster_i[s], cd = cluster_i[d];
  if (cs != cd) atomicAdd(&Ac[(size_t)cs * N_NODES + cd], 1.0f);
}

// ---------- launcher ----------

extern "C" void kernel_launch(void* const* d_in, const int* in_sizes, int n_in,
                              void* d_out, int out_size, void* d_ws, size_t ws_size,
                              hipStream_t stream){
  const float* x     = (const float*)d_in[0];
  const int*   ei    = (const int*)  d_in[1];
  const int*   batch = (const int*)  d_in[2];
  const float* lw    = (const float*)d_in[3];
  const float* lb    = (const float*)d_in[4];

  float* out = (float*)d_out;
  float* Xn  = out;                                       // 8192*256
  float* Ac  = Xn + (size_t)N_NODES * N_FEAT;             // 8192*8192
  float* ob  = Ac + (size_t)N_NODES * N_NODES;            // 8192 (new_batch)
  float* oc  = ob + N_NODES;                              // 8192 (cluster)

  char* w = (char*)d_ws;
  float* p1        = (float*)w; w += (size_t)N_NODES * 4;
  float* p2        = (float*)w; w += (size_t)N_NODES * 4;
  float* e_val     = (float*)w; w += (size_t)N_DIR   * 4;
  int*   cnt       = (int*)  w; w += (size_t)N_NODES * 4;
  int*   cursor    = (int*)  w; w += (size_t)N_NODES * 4;
  int*   row_start = (int*)  w; w += (size_t)(N_NODES + 8) * 4;
  int*   deg       = (int*)  w; w += (size_t)N_NODES * 4;
  int*   cluster_i = (int*)  w; w += (size_t)N_NODES * 4;
  int*   esrc      = (int*)  w; w += (size_t)N_DIR   * 4;
  float* evs       = (float*)w; w += (size_t)N_DIR   * 4;
  unsigned int* pairs = (unsigned int*)w; w += (size_t)N_DIR * 4;
  int*   np        = (int*)  w; w += 64;
  float* y         = (float*)w; w += (size_t)N_NODES * N_FEAT * 4;

  // zero entire output (covers X_new, A_c, new_batch, cluster slots)
  hipMemsetAsync(d_out, 0, (size_t)out_size * sizeof(float), stream);

  k_init  <<<(N_NODES + 255) / 256, 256, 0, stream>>>(cnt, deg, np);
  k_proj  <<<N_NODES, 256, 0, stream>>>(x, lw, p1, p2);
  k_edges <<<N_DIR / 256, 256, 0, stream>>>(ei, p1, p2, lb, e_val, cnt, deg, pairs, np);
  k_scan  <<<1, 1024, 0, stream>>>(cnt, row_start, cursor);
  k_fill  <<<N_DIR / 256, 256, 0, stream>>>(ei, e_val, cursor, esrc, evs);
  k_cc    <<<1, 1024, 0, stream>>>(pairs, np, batch, cluster_i, oc, ob);
  k_y     <<<N_NODES, 256, 0, stream>>>(x, evs, esrc, row_start, deg, y);
  k_xnew  <<<N_NODES / 32, 256, 0, stream>>>(y, cluster_i, Xn);
  k_ac    <<<N_DIR / 256, 256, 0, stream>>>(ei, cluster_i, Ac);
}